// Round 5
// baseline (2307.076 us; speedup 1.0000x reference)
//
#include <hip/hip_runtime.h>

#define B_DIM 2048
#define K_DIM 8192
#define N_DIM 8192
#define NNZ_N 4194304

#define BM 128
#define BN 128
#define BK 64

typedef __attribute__((ext_vector_type(8))) short short8;
typedef __attribute__((ext_vector_type(4))) float f32x4;
typedef __attribute__((ext_vector_type(4))) unsigned short u16x4;

typedef __attribute__((address_space(1))) void gvoid_t;
typedef __attribute__((address_space(3))) void svoid_t;

__device__ __forceinline__ unsigned short f2bf(float f) {
  unsigned u = __float_as_uint(f);
  unsigned r = 0x7fffu + ((u >> 16) & 1u);
  return (unsigned short)((u + r) >> 16);
}
__device__ __forceinline__ float bf2f(unsigned short h) {
  return __uint_as_float(((unsigned)h) << 16);
}

// --- scatter COO values for W rows in [r0, r0+rows) into chunk buffer Wc
// [rows][K_DIM] fp32. atomicAdd sums duplicates (== coalesce()/.at[].add).
__global__ __launch_bounds__(256) void scatter_kernel(
    const int* __restrict__ idx, const float* __restrict__ vals,
    float* __restrict__ Wc, int r0, int rows) {
  int i = blockIdx.x * 256 + threadIdx.x;   // NNZ divisible by 256
  int r = idx[i] - r0;
  if ((unsigned)r < (unsigned)rows) {
    int c = idx[NNZ_N + i];
    atomicAdd(&Wc[(size_t)r * K_DIM + c], vals[i]);
  }
}

// --- split fp32 -> (hi, lo) bf16, 4 elems/thread; count divisible by 1024
__global__ __launch_bounds__(256) void split_kernel(
    const float* __restrict__ src, unsigned short* __restrict__ hi,
    unsigned short* __restrict__ lo) {
  size_t i = (size_t)blockIdx.x * 256 + threadIdx.x;
  f32x4 v = ((const f32x4*)src)[i];
  u16x4 h, l;
#pragma unroll
  for (int j = 0; j < 4; ++j) {
    float f = v[j];
    unsigned short hb = f2bf(f);
    float lf = f - bf2f(hb);
    h[j] = hb;
    l[j] = f2bf(lf);
  }
  ((u16x4*)hi)[i] = h;
  ((u16x4*)lo)[i] = l;
}

// --- fused 3-phase split-bf16 GEMM: C = Xhi*Whi^T + Xhi*Wlo^T + Xlo*Whi^T
// m97-structure: 128x128 tile, BK=64, 4 waves (2x2 of 64x64), 16x16x32 bf16 MFMA,
// global_load_lds width-16 staging, 2-barrier K loop. Relative err ~1e-5.
// whi/wlo hold `ntn*BN` rows (chunk-local); output cols offset by r0.
struct GemmCtx {
  size_t aoff[4], boff[4];
  int wr, wc, fr, fk;
};

__device__ __forceinline__ void gemm_phase(
    const unsigned short* __restrict__ Ap, const unsigned short* __restrict__ Bp,
    unsigned short* As, unsigned short* Bs, const GemmCtx& c, int wid,
    f32x4 acc[4][4]) {
  for (int kt = 0; kt < K_DIM / BK; ++kt) {
    const int k0 = kt * BK;
#pragma unroll
    for (int i = 0; i < 4; ++i) {
      int ch = wid * 4 + i;
      __builtin_amdgcn_global_load_lds(
          (const gvoid_t*)(Ap + c.aoff[i] + k0),
          (svoid_t*)(As + ch * 512), 16, 0, 0);
      __builtin_amdgcn_global_load_lds(
          (const gvoid_t*)(Bp + c.boff[i] + k0),
          (svoid_t*)(Bs + ch * 512), 16, 0, 0);
    }
    __syncthreads();

#pragma unroll
    for (int ks = 0; ks < 2; ++ks) {
      short8 a[4], b[4];
#pragma unroll
      for (int m = 0; m < 4; ++m)
        a[m] = *(const short8*)&As[(c.wr + m * 16 + c.fr) * BK + ks * 32 + c.fk];
#pragma unroll
      for (int n = 0; n < 4; ++n)
        b[n] = *(const short8*)&Bs[(c.wc + n * 16 + c.fr) * BK + ks * 32 + c.fk];
#pragma unroll
      for (int m = 0; m < 4; ++m)
#pragma unroll
        for (int n = 0; n < 4; ++n)
          acc[m][n] = __builtin_amdgcn_mfma_f32_16x16x32_bf16(a[m], b[n], acc[m][n], 0, 0, 0);
    }
    __syncthreads();
  }
}

__global__ __launch_bounds__(256, 2) void gemm_split_kernel(
    const unsigned short* __restrict__ xhi, const unsigned short* __restrict__ xlo,
    const unsigned short* __restrict__ whi, const unsigned short* __restrict__ wlo,
    float* __restrict__ out, int r0, unsigned ntn) {
  __shared__ unsigned short As[BM * BK];  // [128][64] row-major
  __shared__ unsigned short Bs[BN * BK];

  const int tid = threadIdx.x;
  const int lane = tid & 63;
  const int wid = tid >> 6;

  const int tile_m = blockIdx.x / ntn;
  const int tile_n = blockIdx.x % ntn;
  const int m0 = tile_m * BM;
  const int n0 = tile_n * BN;   // chunk-local W row

  // staging: chunk ch = wid*4+i covers rows ch*8..ch*8+7; each lane stages 16B.
  // global_load_lds dest is wave-uniform base; HW writes base+lane*16 ->
  // row-major [8][128B], matching the per-lane global addresses (guide §5).
  const int st_row = lane >> 3;
  const int st_col = (lane & 7) * 8;

  GemmCtx c;
#pragma unroll
  for (int i = 0; i < 4; ++i) {
    int ch = wid * 4 + i;
    c.aoff[i] = (size_t)(m0 + ch * 8 + st_row) * K_DIM + st_col;
    c.boff[i] = (size_t)(n0 + ch * 8 + st_row) * K_DIM + st_col;
  }
  c.fr = lane & 15;            // row within 16x16 frag
  c.fk = (lane >> 4) * 8;      // k offset within 32
  c.wr = (wid >> 1) * 64;      // wave row offset in tile
  c.wc = (wid & 1) * 64;       // wave col offset in tile

  f32x4 acc[4][4];
#pragma unroll
  for (int i = 0; i < 4; ++i)
#pragma unroll
    for (int j = 0; j < 4; ++j) acc[i][j] = (f32x4)0.0f;

  gemm_phase(xhi, whi, As, Bs, c, wid, acc);
  gemm_phase(xhi, wlo, As, Bs, c, wid, acc);
  gemm_phase(xlo, whi, As, Bs, c, wid, acc);

  // epilogue: D layout col=lane&15, row=(lane>>4)*4+reg (m89/m91-verified)
  const int orow = m0 + c.wr + (lane >> 4) * 4;
  const int ocol = r0 + n0 + c.wc + c.fr;
#pragma unroll
  for (int m = 0; m < 4; ++m)
#pragma unroll
    for (int n = 0; n < 4; ++n)
#pragma unroll
      for (int j = 0; j < 4; ++j)
        out[(size_t)(orow + m * 16 + j) * N_DIM + ocol + n * 16] = acc[m][n][j];
}

extern "C" void kernel_launch(void* const* d_in, const int* in_sizes, int n_in,
                              void* d_out, int out_size, void* d_ws, size_t ws_size,
                              hipStream_t stream) {
  const float* x = (const float*)d_in[0];
  const float* vals = (const float*)d_in[1];
  const int* idx = (const int*)d_in[2];
  float* out = (float*)d_out;

  char* ws = (char*)d_ws;
  const size_t MB = 1024ull * 1024ull;

  // x split buffers: 64 MB total (always present)
  unsigned short* Xhi = (unsigned short*)ws;              // 32 MB
  unsigned short* Xlo = (unsigned short*)(ws + 32 * MB);  // 32 MB
  split_kernel<<<(B_DIM * (size_t)K_DIM / 4) / 256, 256, 0, stream>>>(x, Xhi, Xlo);

  if (ws_size >= 384 * MB) {
    // Tier A: full bf16 W planes + 64 MB fp32 bounce chunk. Peak 384 MB.
    unsigned short* Whi = (unsigned short*)(ws + 64 * MB);   // 128 MB
    unsigned short* Wlo = (unsigned short*)(ws + 192 * MB);  // 128 MB
    float* Wc = (float*)(ws + 320 * MB);                     // 64 MB (2048 rows)
    const int C = 2048;
    for (int r0 = 0; r0 < N_DIM; r0 += C) {
      hipMemsetAsync(Wc, 0, (size_t)C * K_DIM * sizeof(float), stream);
      scatter_kernel<<<NNZ_N / 256, 256, 0, stream>>>(idx, vals, Wc, r0, C);
      split_kernel<<<((size_t)C * K_DIM / 4) / 256, 256, 0, stream>>>(
          Wc, Whi + (size_t)r0 * K_DIM, Wlo + (size_t)r0 * K_DIM);
    }
    gemm_split_kernel<<<(B_DIM / BM) * (N_DIM / BN), 256, 0, stream>>>(
        Xhi, Xlo, Whi, Wlo, out, 0, N_DIM / BN);
  } else {
    // Tier B: chunk-resident hi/lo + per-chunk GEMM. Peak = 64MB + C*64KB.
    int C = 2048;
    while (C > 256 && 64 * MB + (size_t)C * K_DIM * 8 > ws_size) C >>= 1;
    float* Wc = (float*)(ws + 64 * MB);                          // C*32KB
    unsigned short* WcHi = (unsigned short*)(ws + 64 * MB + (size_t)C * K_DIM * 4);
    unsigned short* WcLo = WcHi + (size_t)C * K_DIM;
    for (int r0 = 0; r0 < N_DIM; r0 += C) {
      hipMemsetAsync(Wc, 0, (size_t)C * K_DIM * sizeof(float), stream);
      scatter_kernel<<<NNZ_N / 256, 256, 0, stream>>>(idx, vals, Wc, r0, C);
      split_kernel<<<((size_t)C * K_DIM / 4) / 256, 256, 0, stream>>>(Wc, WcHi, WcLo);
      gemm_split_kernel<<<(B_DIM / BM) * (C / BN), 256, 0, stream>>>(
          Xhi, Xlo, WcHi, WcLo, out, r0, C / BN);
    }
  }
}

// Round 7
// 2292.579 us; speedup vs baseline: 1.0063x; 1.0063x over previous
//
#include <hip/hip_runtime.h>

#define B_DIM 2048
#define K_DIM 8192
#define N_DIM 8192
#define NNZ_N 4194304

#define BM 128
#define BN 128
#define BK 64

typedef __attribute__((ext_vector_type(8))) short short8;
typedef __attribute__((ext_vector_type(4))) float f32x4;
typedef __attribute__((ext_vector_type(4))) unsigned short u16x4;

typedef __attribute__((address_space(1))) void gvoid_t;
typedef __attribute__((address_space(3))) void svoid_t;

__device__ __forceinline__ unsigned short f2bf(float f) {
  unsigned u = __float_as_uint(f);
  unsigned r = 0x7fffu + ((u >> 16) & 1u);
  return (unsigned short)((u + r) >> 16);
}
__device__ __forceinline__ float bf2f(unsigned short h) {
  return __uint_as_float(((unsigned)h) << 16);
}

// --- scatter COO values for W rows in [r0, r0+rows) into chunk buffer Wc
// [rows][K_DIM] fp32. Sums duplicates (== coalesce()/.at[].add).
// unsafeAtomicAdd -> native global_atomic_add_f32 (fire-and-forget, no CAS
// loop; denormal-flush irrelevant for ~0.1-magnitude values). Default
// atomicAdd(float*) lowers to a CAS loop on CDNA -> latency-bound scatter.
__global__ __launch_bounds__(256) void scatter_kernel(
    const int* __restrict__ idx, const float* __restrict__ vals,
    float* __restrict__ Wc, int r0, int rows) {
  int i = blockIdx.x * 256 + threadIdx.x;   // NNZ divisible by 256
  int r = idx[i] - r0;
  if ((unsigned)r < (unsigned)rows) {
    int c = idx[NNZ_N + i];
    unsafeAtomicAdd(&Wc[(size_t)r * K_DIM + c], vals[i]);
  }
}

// --- split fp32 -> (hi, lo) bf16, 4 elems/thread; count divisible by 1024
__global__ __launch_bounds__(256) void split_kernel(
    const float* __restrict__ src, unsigned short* __restrict__ hi,
    unsigned short* __restrict__ lo) {
  size_t i = (size_t)blockIdx.x * 256 + threadIdx.x;
  f32x4 v = ((const f32x4*)src)[i];
  u16x4 h, l;
#pragma unroll
  for (int j = 0; j < 4; ++j) {
    float f = v[j];
    unsigned short hb = f2bf(f);
    float lf = f - bf2f(hb);
    h[j] = hb;
    l[j] = f2bf(lf);
  }
  ((u16x4*)hi)[i] = h;
  ((u16x4*)lo)[i] = l;
}

// --- fused 3-phase split-bf16 GEMM: C = Xhi*Whi^T + Xhi*Wlo^T + Xlo*Whi^T
// m97-structure: 128x128 tile, BK=64, 4 waves (2x2 of 64x64), 16x16x32 bf16 MFMA,
// global_load_lds width-16 staging, 2-barrier K loop.
// Measured r5: 512 us = 1.61 PF = 64% dense peak; FETCH 508 MB ~= minimal.
struct GemmCtx {
  size_t aoff[4], boff[4];
  int wr, wc, fr, fk;
};

__device__ __forceinline__ void gemm_phase(
    const unsigned short* __restrict__ Ap, const unsigned short* __restrict__ Bp,
    unsigned short* As, unsigned short* Bs, const GemmCtx& c, int wid,
    f32x4 acc[4][4]) {
  for (int kt = 0; kt < K_DIM / BK; ++kt) {
    const int k0 = kt * BK;
#pragma unroll
    for (int i = 0; i < 4; ++i) {
      int ch = wid * 4 + i;
      __builtin_amdgcn_global_load_lds(
          (const gvoid_t*)(Ap + c.aoff[i] + k0),
          (svoid_t*)(As + ch * 512), 16, 0, 0);
      __builtin_amdgcn_global_load_lds(
          (const gvoid_t*)(Bp + c.boff[i] + k0),
          (svoid_t*)(Bs + ch * 512), 16, 0, 0);
    }
    __syncthreads();

#pragma unroll
    for (int ks = 0; ks < 2; ++ks) {
      short8 a[4], b[4];
#pragma unroll
      for (int m = 0; m < 4; ++m)
        a[m] = *(const short8*)&As[(c.wr + m * 16 + c.fr) * BK + ks * 32 + c.fk];
#pragma unroll
      for (int n = 0; n < 4; ++n)
        b[n] = *(const short8*)&Bs[(c.wc + n * 16 + c.fr) * BK + ks * 32 + c.fk];
#pragma unroll
      for (int m = 0; m < 4; ++m)
#pragma unroll
        for (int n = 0; n < 4; ++n)
          acc[m][n] = __builtin_amdgcn_mfma_f32_16x16x32_bf16(a[m], b[n], acc[m][n], 0, 0, 0);
    }
    __syncthreads();
  }
}

__global__ __launch_bounds__(256, 2) void gemm_split_kernel(
    const unsigned short* __restrict__ xhi, const unsigned short* __restrict__ xlo,
    const unsigned short* __restrict__ whi, const unsigned short* __restrict__ wlo,
    float* __restrict__ out, int r0, unsigned ntn) {
  __shared__ unsigned short As[BM * BK];  // [128][64] row-major
  __shared__ unsigned short Bs[BN * BK];

  const int tid = threadIdx.x;
  const int lane = tid & 63;
  const int wid = tid >> 6;

  const int tile_m = blockIdx.x / ntn;
  const int tile_n = blockIdx.x % ntn;
  const int m0 = tile_m * BM;
  const int n0 = tile_n * BN;   // chunk-local W row

  // staging: chunk ch = wid*4+i covers rows ch*8..ch*8+7; each lane stages 16B.
  // global_load_lds dest is wave-uniform base; HW writes base+lane*16 ->
  // row-major [8][128B], matching the per-lane global addresses (guide §5).
  const int st_row = lane >> 3;
  const int st_col = (lane & 7) * 8;

  GemmCtx c;
#pragma unroll
  for (int i = 0; i < 4; ++i) {
    int ch = wid * 4 + i;
    c.aoff[i] = (size_t)(m0 + ch * 8 + st_row) * K_DIM + st_col;
    c.boff[i] = (size_t)(n0 + ch * 8 + st_row) * K_DIM + st_col;
  }
  c.fr = lane & 15;            // row within 16x16 frag
  c.fk = (lane >> 4) * 8;      // k offset within 32
  c.wr = (wid >> 1) * 64;      // wave row offset in tile
  c.wc = (wid & 1) * 64;       // wave col offset in tile

  f32x4 acc[4][4];
#pragma unroll
  for (int i = 0; i < 4; ++i)
#pragma unroll
    for (int j = 0; j < 4; ++j) acc[i][j] = (f32x4)0.0f;

  gemm_phase(xhi, whi, As, Bs, c, wid, acc);
  gemm_phase(xhi, wlo, As, Bs, c, wid, acc);
  gemm_phase(xlo, whi, As, Bs, c, wid, acc);

  // epilogue: D layout col=lane&15, row=(lane>>4)*4+reg (m89/m91-verified)
  const int orow = m0 + c.wr + (lane >> 4) * 4;
  const int ocol = r0 + n0 + c.wc + c.fr;
#pragma unroll
  for (int m = 0; m < 4; ++m)
#pragma unroll
    for (int n = 0; n < 4; ++n)
#pragma unroll
      for (int j = 0; j < 4; ++j)
        out[(size_t)(orow + m * 16 + j) * N_DIM + ocol + n * 16] = acc[m][n][j];
}

extern "C" void kernel_launch(void* const* d_in, const int* in_sizes, int n_in,
                              void* d_out, int out_size, void* d_ws, size_t ws_size,
                              hipStream_t stream) {
  const float* x = (const float*)d_in[0];
  const float* vals = (const float*)d_in[1];
  const int* idx = (const int*)d_in[2];
  float* out = (float*)d_out;

  char* ws = (char*)d_ws;
  const size_t MB = 1024ull * 1024ull;

  // x split buffers: 64 MB total (always present)
  unsigned short* Xhi = (unsigned short*)ws;              // 32 MB
  unsigned short* Xlo = (unsigned short*)(ws + 32 * MB);  // 32 MB
  split_kernel<<<(B_DIM * (size_t)K_DIM / 4) / 256, 256, 0, stream>>>(x, Xhi, Xlo);

  if (ws_size >= 384 * MB) {
    // Tier A: full bf16 W planes + 64 MB fp32 bounce chunk. Peak 384 MB.
    unsigned short* Whi = (unsigned short*)(ws + 64 * MB);   // 128 MB
    unsigned short* Wlo = (unsigned short*)(ws + 192 * MB);  // 128 MB
    float* Wc = (float*)(ws + 320 * MB);                     // 64 MB (2048 rows)
    const int C = 2048;
    for (int r0 = 0; r0 < N_DIM; r0 += C) {
      hipMemsetAsync(Wc, 0, (size_t)C * K_DIM * sizeof(float), stream);
      scatter_kernel<<<NNZ_N / 256, 256, 0, stream>>>(idx, vals, Wc, r0, C);
      split_kernel<<<((size_t)C * K_DIM / 4) / 256, 256, 0, stream>>>(
          Wc, Whi + (size_t)r0 * K_DIM, Wlo + (size_t)r0 * K_DIM);
    }
    gemm_split_kernel<<<(B_DIM / BM) * (N_DIM / BN), 256, 0, stream>>>(
        Xhi, Xlo, Whi, Wlo, out, 0, N_DIM / BN);
  } else {
    // Tier B: chunk-resident hi/lo + per-chunk GEMM. Peak = 64MB + C*64KB.
    int C = 2048;
    while (C > 256 && 64 * MB + (size_t)C * K_DIM * 8 > ws_size) C >>= 1;
    float* Wc = (float*)(ws + 64 * MB);                          // C*32KB
    unsigned short* WcHi = (unsigned short*)(ws + 64 * MB + (size_t)C * K_DIM * 4);
    unsigned short* WcLo = WcHi + (size_t)C * K_DIM;
    for (int r0 = 0; r0 < N_DIM; r0 += C) {
      hipMemsetAsync(Wc, 0, (size_t)C * K_DIM * sizeof(float), stream);
      scatter_kernel<<<NNZ_N / 256, 256, 0, stream>>>(idx, vals, Wc, r0, C);
      split_kernel<<<((size_t)C * K_DIM / 4) / 256, 256, 0, stream>>>(Wc, WcHi, WcLo);
      gemm_split_kernel<<<(B_DIM / BM) * (C / BN), 256, 0, stream>>>(
          Xhi, Xlo, WcHi, WcLo, out, r0, C / BN);
    }
  }
}